// Round 15
// baseline (39.740 us; speedup 1.0000x reference)
//
#include <hip/hip_runtime.h>
#include <math.h>
#include <stdint.h>

// NonLinearLayer: piecewise-quadratic CDF flow on a geometric mesh.
// x:(N,16) f32, pdj:(N,1), sldj:(N,1), log_p:(63,16), mesh_norm:(65,), elmt_size:(64,)
// out = concat(x_out (N*16), pdj_out (N), sldj_out (N))
//
// R15: ASYNC STAGING via global_load_lds (cp.async analog). Register-destination
// prefetch failed 5 ways (compiler serializes to save VGPRs; asm pinning
// faults). global_load_lds has NO destination register -> issue is decoupled
// from consumption. Per-wave ping-pong ring in LDS (barrier-free after setup):
// stage block k+1 (2KB x + 256B pdj/sldj, 3 insts) while computing block k.
// Outstanding reads/wave: 36B -> 2.3KB (~60x); 16 waves/CU -> 37KB/CU >> 6KB
// Little's-law need. Dense lane->16B chunks keep DMA writes and ds_read_b128
// readback conflict-free; lane i owns quad (i&1) of tile T+(i>>1) so the
// point product is shfl_xor(1),shfl_xor(2) and all stores stay coalesced.
// vmcnt(3) wait is safe: exactly the 3 next-stage loads (fenced by
// sched_barrier) are issued after the target stage; in-order retirement.

namespace {
constexpr int DIM = 16;
constexpr int ME  = 64;
constexpr float BOUNDF = 50.0f;
// K1 = 0.2/one_step = 0.02*(1.2^32-1);  INV_L2R = 1/log2(1.2)
constexpr float K1      = 6.8164378f;
constexpr float INV_L2R = 3.8017840f;
constexpr int NBIN = 66;                   // sentinel 0, real 1..64, sentinel 65
constexpr int ROWF = 68;                   // floats per row: 16 dims * 4 + pad
constexpr int COEF_FLOATS = NBIN * ROWF;   // 4488 floats
constexpr int BLOCK = 256;                 // 4 waves
constexpr int NWAVE = 4;
constexpr int STAGF = 576;                 // floats/stage buf: 512 x + 64 ps
constexpr int GRID_CAP = 1024;             // 4 blocks/CU resident
}

__device__ __forceinline__ void gl_lds16(const float* g, float* l) {
  __builtin_amdgcn_global_load_lds(
      (const __attribute__((address_space(1))) void*)g,
      (__attribute__((address_space(3))) void*)l, 16, 0, 0);
}
__device__ __forceinline__ void gl_lds4(const float* g, float* l) {
  __builtin_amdgcn_global_load_lds(
      (const __attribute__((address_space(1))) void*)g,
      (__attribute__((address_space(3))) void*)l, 4, 0, 0);
}

__global__ __launch_bounds__(BLOCK) void nll_kernel(
    const float* __restrict__ x,
    const float* __restrict__ pdj,
    const float* __restrict__ sldj,
    const float* __restrict__ log_p,
    const float* __restrict__ mesh_norm,
    float* __restrict__ out,
    int npts, int npairs)
{
  __shared__ __align__(16) float co[COEF_FLOATS];
  __shared__ __align__(16) float stag[NWAVE * 2 * STAGF];

  const int tid  = threadIdx.x;
  const int wv   = tid >> 6;
  const int lane = tid & 63;
  const int tpg  = gridDim.x * BLOCK;

  float* stg[2] = {&stag[(wv * 2 + 0) * STAGF], &stag[(wv * 2 + 1) * STAGF]};

  // stage issue for tile-block [T, T+64) into buf (3 global_load_lds, no regs)
  auto stage_issue = [&](int T, float* buf) {
    int gi = 8 * T + 4 * lane;                 // float idx of lane's 16B chunk
    const int gmax = 8 * npairs - 4;
    int g0 = gi <= gmax ? gi : gmax;
    int g1 = (gi + 256) <= gmax ? gi + 256 : gmax;
    gl_lds16(x + g0, buf);                     // HW dest: buf + lane*16B
    gl_lds16(x + g1, buf + 256);
    const int P = T >> 1;
    int pi = P + (lane & 31); if (pi >= npts) pi = npts - 1;
    gl_lds4((lane < 32 ? pdj : sldj) + pi, buf + 512);  // HW dest: +lane*4B
  };

  // ---- prologue: stage first block BEFORE setup (overlaps table build) ----
  int T = blockIdx.x * BLOCK + wv * 64;
  const bool wave_live = T < npairs;
  if (wave_live) stage_issue(T, stg[0]);
  __builtin_amdgcn_sched_barrier(0);

  // ---- setup: table build, 4 dims/wave, direct global reads, one barrier ----
  {
    const float mj  = mesh_norm[lane];
    const float mj1 = mesh_norm[lane + 1];
    const float mj2 = mesh_norm[(lane + 2 > ME) ? ME : (lane + 2)];
    const float es0 = mesh_norm[1];            // mesh_norm[0] == 0
    const float h = mj1 - mj;
#pragma unroll
    for (int i = 0; i < 4; ++i) {
      const int d = 4 * wv + i;
      const float ep = (lane < 63) ? __expf(log_p[lane * DIM + d]) : 0.f;
      float ss = (lane < 63) ? ep * (mj2 - mj) : 0.f;
      ss += __shfl_xor(ss, 1);  ss += __shfl_xor(ss, 2);  ss += __shfl_xor(ss, 4);
      ss += __shfl_xor(ss, 8);  ss += __shfl_xor(ss, 16); ss += __shfl_xor(ss, 32);
      const float scale = (1.0f - es0) / (0.5f * ss);
      const float cur = (lane < 63) ? ep * scale : 1.0f;   // pdf_norm[lane+1]
      float prev = __shfl_up(cur, 1);                       // pdf_norm[lane]
      if (lane == 0) prev = 1.0f;
      const float cell = (prev + cur) * 0.5f * h;
      float v = cell, o;
      o = __shfl_up(v, 1);  if (lane >= 1)  v += o;
      o = __shfl_up(v, 2);  if (lane >= 2)  v += o;
      o = __shfl_up(v, 4);  if (lane >= 4)  v += o;
      o = __shfl_up(v, 8);  if (lane >= 8)  v += o;
      o = __shfl_up(v, 16); if (lane >= 16) v += o;
      o = __shfl_up(v, 32); if (lane >= 32) v += o;
      const float F = v - cell;                             // F_ref[lane]
      const float A = 0.5f * (cur - prev) / h;
      const float B = fmaf(-(A + A), mj, prev);
      const float D = fmaf(mj, fmaf(mj, A, -prev), F);
      *reinterpret_cast<float4*>(&co[(lane + 1) * ROWF + 4 * d]) =
          make_float4(A, B, D, A + A);
    }
    if (tid < 32) {   // sentinel rows: (0,1,0,0) -> y=xn, dt=1 exactly
      const int row = (tid >> 4) ? (NBIN - 1) : 0;
      const int d = tid & 15;
      *reinterpret_cast<float4*>(&co[row * ROWF + 4 * d]) =
          make_float4(0.f, 1.f, 0.f, 0.f);
    }
  }
  __syncthreads();

  if (!wave_live) return;

  float4* __restrict__ out4 = reinterpret_cast<float4*>(out);
  const int np16 = npts * DIM;

  // compute one 32-tile group from the staged buffer
  auto do_group = [&](int g, const float* sbuf, int Tb) {
    const int half = lane >> 1;              // 0..31
    const int q    = lane & 1;
    const int tt   = Tb + g * 32 + half;     // this lane's tile
    const bool vld = tt < npairs;
    const float4 xv = *reinterpret_cast<const float4*>(&sbuf[g * 256 + 4 * lane]);
    const int hh = half & 1;                 // tile parity (Tb even)
    const int dbase = hh * 32 + q * 16;
    const float vals[4] = {xv.x, xv.y, xv.z, xv.w};
    float xn[4]; int idx[4];
#pragma unroll
    for (int j = 0; j < 4; ++j) {
      const float val = vals[j];
      xn[j] = fmaf(val, 0.01f, 0.5f);
      const float u = fmaf(fabsf(val), K1, 1.0f);
      const float n = __log2f(u) * INV_L2R;
      int k = 32 + (int)ceilf(copysignf(n, val));
      k = k < 0 ? 0 : (k > NBIN - 1 ? NBIN - 1 : k);
      idx[j] = k * ROWF + dbase + (j << 2);
    }
    float4 cf[4];
#pragma unroll
    for (int j = 0; j < 4; ++j)
      cf[j] = *reinterpret_cast<const float4*>(&co[idx[j]]);
    float yv[4], dt[4];
#pragma unroll
    for (int j = 0; j < 4; ++j) {
      const float z = xn[j];
      yv[j] = fmaf(fmaf(z, fmaf(z, cf[j].x, cf[j].y), cf[j].z), 2.0f * BOUNDF, -BOUNDF);
      dt[j] = fmaf(z, cf[j].w, cf[j].y);
    }
    float pr = (dt[0] * dt[1]) * (dt[2] * dt[3]);
    if (vld) out4[2 * Tb + g * 64 + lane] = make_float4(yv[0], yv[1], yv[2], yv[3]);
    pr *= __shfl_xor(pr, 1);
    pr *= __shfl_xor(pr, 2);                 // full 16-dim point product
    const int pw = g * 16 + (lane >> 2);     // wave-point index 0..31
    const int p  = (Tb >> 1) + pw;
    if (vld && (lane & 3) == 0) out[np16 + p] = sbuf[512 + pw] * pr;
    if (vld && (lane & 3) == 1) out[np16 + npts + p] = sbuf[544 + pw] + __logf(pr);
  };

  int b = 0;
  while (T < npairs) {
    const int Tn = T + tpg;
    if (Tn < npairs) {
      stage_issue(Tn, stg[b ^ 1]);
      __builtin_amdgcn_sched_barrier(0);
      asm volatile("s_waitcnt vmcnt(3)" ::: "memory");   // block T's 3 loads done
    } else {
      asm volatile("s_waitcnt vmcnt(0)" ::: "memory");
    }
    __builtin_amdgcn_sched_barrier(0);
    do_group(0, stg[b], T);
    do_group(1, stg[b], T);
    T = Tn; b ^= 1;
  }
  asm volatile("s_waitcnt vmcnt(0)" ::: "memory");       // drain before endpgm
}

extern "C" void kernel_launch(void* const* d_in, const int* in_sizes, int n_in,
                              void* d_out, int out_size, void* d_ws, size_t ws_size,
                              hipStream_t stream) {
  const float* x    = (const float*)d_in[0];
  const float* pdj  = (const float*)d_in[1];
  const float* sldj = (const float*)d_in[2];
  const float* lp   = (const float*)d_in[3];
  const float* mesh = (const float*)d_in[4];
  float* out = (float*)d_out;

  const int npts   = in_sizes[0] / DIM;
  const int npairs = npts * 2;
  int grid = (npairs + BLOCK - 1) / BLOCK;
  if (grid > GRID_CAP) grid = GRID_CAP;

  hipLaunchKernelGGL(nll_kernel, dim3(grid), dim3(BLOCK), 0, stream,
                     x, pdj, sldj, lp, mesh, out, npts, npairs);
}

// Round 16
// 39.404 us; speedup vs baseline: 1.0085x; 1.0085x over previous
//
#include <hip/hip_runtime.h>
#include <math.h>
#include <stdint.h>

// NonLinearLayer: piecewise-quadratic CDF flow on a geometric mesh.
// x:(N,16) f32, pdj:(N,1), sldj:(N,1), log_p:(63,16), mesh_norm:(65,), elmt_size:(64,)
// out = concat(x_out (N*16), pdj_out (N), sldj_out (N))
//
// R16: R14's no-loop one-task-per-thread structure (the only structural win of
// the session) widened to ONE FULL POINT per thread: 64B of x issued per lane
// at wave start (2x R14), half the wave count (less ramp/drain), no shuffles,
// one __logf per point, all pdj/sldj traffic coalesced. R3's full-point
// failure was grid-stride register recycling; no-loop sidesteps it.
// Cached (not NT) stores: lane-stride-64B layout merges fine in L2 (R3:
// WRITE=73.7MB; R7 showed amplification is NT-specific).
// Sentinel bins keep the body branch-free.

namespace {
constexpr int DIM = 16;
constexpr int ME  = 64;
constexpr float BOUNDF = 50.0f;
// K1 = 0.2/one_step = 0.02*(1.2^32-1);  INV_L2R = 1/log2(1.2)
constexpr float K1      = 6.8164378f;
constexpr float INV_L2R = 3.8017840f;
constexpr int NBIN = 66;                        // sentinel 0, real 1..64, sentinel 65
constexpr int ROWF = 68;                        // floats per row: 16 dims * 4 + pad
constexpr int COEF_FLOATS = NBIN * ROWF;        // 4488 floats = 17952 B
constexpr int BLOCK = 512;                      // 8 waves
}

__global__ __launch_bounds__(BLOCK) void nll_kernel(
    const float* __restrict__ x,
    const float* __restrict__ pdj,
    const float* __restrict__ sldj,
    const float* __restrict__ log_p,
    const float* __restrict__ mesh_norm,
    float* __restrict__ out,
    int npts)
{
  __shared__ __align__(16) float co[COEF_FLOATS];

  const int tid  = threadIdx.x;
  const int wv   = tid >> 6;        // 0..7
  const int lane = tid & 63;

  const int p = blockIdx.x * BLOCK + tid;
  const bool live = p < npts;

  // ---- main-body loads first: independent of setup, hide under it ----
  const float4* __restrict__ x4 = reinterpret_cast<const float4*>(x);
  float4 X0, X1, X2, X3;
  float pv = 0.f, sv = 0.f;
  if (live) {
    X0 = x4[4 * p + 0];
    X1 = x4[4 * p + 1];
    X2 = x4[4 * p + 2];
    X3 = x4[4 * p + 3];
    pv = pdj[p];
    sv = sldj[p];
  }

  // ---- setup: 2 dims per wave, direct global reads, one barrier ----
  {
    const float mj  = mesh_norm[lane];
    const float mj1 = mesh_norm[lane + 1];
    const float mj2 = mesh_norm[(lane + 2 > ME) ? ME : (lane + 2)];
    const float es0 = mesh_norm[1];            // mesh_norm[0] == 0
    const float h = mj1 - mj;
#pragma unroll
    for (int i = 0; i < 2; ++i) {
      const int d = 2 * wv + i;
      const float ep = (lane < 63) ? __expf(log_p[lane * DIM + d]) : 0.f;
      float ss = (lane < 63) ? ep * (mj2 - mj) : 0.f;
      ss += __shfl_xor(ss, 1);  ss += __shfl_xor(ss, 2);  ss += __shfl_xor(ss, 4);
      ss += __shfl_xor(ss, 8);  ss += __shfl_xor(ss, 16); ss += __shfl_xor(ss, 32);
      const float scale = (1.0f - es0) / (0.5f * ss);
      const float cur = (lane < 63) ? ep * scale : 1.0f;   // pdf_norm[lane+1]
      float prev = __shfl_up(cur, 1);                       // pdf_norm[lane]
      if (lane == 0) prev = 1.0f;
      const float cell = (prev + cur) * 0.5f * h;
      float v = cell, o;
      o = __shfl_up(v, 1);  if (lane >= 1)  v += o;
      o = __shfl_up(v, 2);  if (lane >= 2)  v += o;
      o = __shfl_up(v, 4);  if (lane >= 4)  v += o;
      o = __shfl_up(v, 8);  if (lane >= 8)  v += o;
      o = __shfl_up(v, 16); if (lane >= 16) v += o;
      o = __shfl_up(v, 32); if (lane >= 32) v += o;
      const float F = v - cell;                             // exclusive prefix = F_ref[lane]
      const float A = 0.5f * (cur - prev) / h;
      const float B = fmaf(-(A + A), mj, prev);
      const float D = fmaf(mj, fmaf(mj, A, -prev), F);
      *reinterpret_cast<float4*>(&co[(lane + 1) * ROWF + 4 * d]) =
          make_float4(A, B, D, A + A);
    }
    // sentinel rows 0 and 65: (A,B,D,2A) = (0,1,0,0) -> y=xn, dt=1 exactly
    if (tid < 32) {
      const int row = (tid >> 4) ? (NBIN - 1) : 0;
      const int d = tid & 15;
      *reinterpret_cast<float4*>(&co[row * ROWF + 4 * d]) =
          make_float4(0.f, 1.f, 0.f, 0.f);
    }
  }
  __syncthreads();

  if (!live) return;

  // ---- one full point (16 dims) per thread ----
  float4* __restrict__ out4 = reinterpret_cast<float4*>(out);
  const int np16 = npts * DIM;

  float vals[16];
  *reinterpret_cast<float4*>(&vals[0])  = X0;
  *reinterpret_cast<float4*>(&vals[4])  = X1;
  *reinterpret_cast<float4*>(&vals[8])  = X2;
  *reinterpret_cast<float4*>(&vals[12]) = X3;

  float xn[16];
  int   idx[16];
#pragma unroll
  for (int j = 0; j < 16; ++j) {
    const float val = vals[j];
    xn[j] = fmaf(val, 0.01f, 0.5f);
    const float u = fmaf(fabsf(val), K1, 1.0f);
    const float n = __log2f(u) * INV_L2R;
    int k = 32 + (int)ceilf(copysignf(n, val));   // searchsorted k (analytic)
    k = k < 0 ? 0 : (k > NBIN - 1 ? NBIN - 1 : k);
    idx[j] = k * ROWF + (j << 2);
  }

  float4 cf[16];
#pragma unroll
  for (int j = 0; j < 16; ++j)
    cf[j] = *reinterpret_cast<const float4*>(&co[idx[j]]);

  float yv[16], dt[16];
#pragma unroll
  for (int j = 0; j < 16; ++j) {
    const float z = xn[j];
    yv[j] = fmaf(fmaf(z, fmaf(z, cf[j].x, cf[j].y), cf[j].z), 2.0f * BOUNDF, -BOUNDF);
    dt[j] = fmaf(z, cf[j].w, cf[j].y);
  }
  const float prod = (((dt[0] * dt[1]) * (dt[2] * dt[3])) *
                      ((dt[4] * dt[5]) * (dt[6] * dt[7]))) *
                     (((dt[8] * dt[9]) * (dt[10] * dt[11])) *
                      ((dt[12] * dt[13]) * (dt[14] * dt[15])));

  out4[4 * p + 0] = make_float4(yv[0],  yv[1],  yv[2],  yv[3]);
  out4[4 * p + 1] = make_float4(yv[4],  yv[5],  yv[6],  yv[7]);
  out4[4 * p + 2] = make_float4(yv[8],  yv[9],  yv[10], yv[11]);
  out4[4 * p + 3] = make_float4(yv[12], yv[13], yv[14], yv[15]);
  out[np16 + p]        = pv * prod;
  out[np16 + npts + p] = sv + __logf(prod);
}

extern "C" void kernel_launch(void* const* d_in, const int* in_sizes, int n_in,
                              void* d_out, int out_size, void* d_ws, size_t ws_size,
                              hipStream_t stream) {
  const float* x    = (const float*)d_in[0];
  const float* pdj  = (const float*)d_in[1];
  const float* sldj = (const float*)d_in[2];
  const float* lp   = (const float*)d_in[3];
  const float* mesh = (const float*)d_in[4];
  float* out = (float*)d_out;

  const int npts = in_sizes[0] / DIM;
  const int grid = (npts + BLOCK - 1) / BLOCK;    // 2048 @ 1M points

  hipLaunchKernelGGL(nll_kernel, dim3(grid), dim3(BLOCK), 0, stream,
                     x, pdj, sldj, lp, mesh, out, npts);
}

// Round 17
// 32.600 us; speedup vs baseline: 1.2190x; 1.2087x over previous
//
#include <hip/hip_runtime.h>
#include <math.h>
#include <stdint.h>

// NonLinearLayer: piecewise-quadratic CDF flow on a geometric mesh.
// x:(N,16) f32, pdj:(N,1), sldj:(N,1), log_p:(63,16), mesh_norm:(65,), elmt_size:(64,)
// out = concat(x_out (N*16), pdj_out (N), sldj_out (N))
//
// FINAL (R14 structure, session best 32.47us): one HALF-POINT (8 dims) per
// thread, no grid-stride loop — HW block refill gives each wave an immediate
// x-load at wave start (deep natural MLP; the only structural change that
// moved rocprof dur, 44 vs 47-51us). Fused cheap setup: block=512 (8 waves,
// 2 dims/wave shuffle-scan), inputs read straight from global (L2-resident),
// one barrier. Analytic bin index (geometric mesh: boundary i at
// 1+K1*|x| = 1.2^|i|) — no searchsorted; continuity across bin boundaries
// bounds the +-1-misclassification error at ~1e-5. Sentinel bins (rows 0/65
// = (0,1,0,0)) make the uncovered path fall out of the quadratic exactly
// (y=xn, dt=1) — branch-free body.
// Session-falsified (do not retry): NT stores (2.2x write amplification on
// non-interleaved layouts; no FETCH change on interleaved), register-pinned
// multi-tile prefetch (compiler serializes or faults), LDS async staging via
// global_load_lds (bank fights + occupancy loss), full-point-per-thread
// (store layout + 16 serial gathers), two-kernel setup split (dispatch
// serialization).

namespace {
constexpr int DIM = 16;
constexpr int ME  = 64;
constexpr float BOUNDF = 50.0f;
// K1 = 0.2/one_step = 0.02*(1.2^32-1);  INV_L2R = 1/log2(1.2)
constexpr float K1      = 6.8164378f;
constexpr float INV_L2R = 3.8017840f;
constexpr int NBIN = 66;                        // sentinel 0, real 1..64, sentinel 65
constexpr int ROWF = 68;                        // floats per row: 16 dims * 4 + pad
constexpr int COEF_FLOATS = NBIN * ROWF;        // 4488 floats = 17952 B
constexpr int BLOCK = 512;
}

__global__ __launch_bounds__(BLOCK) void nll_kernel(
    const float* __restrict__ x,
    const float* __restrict__ pdj,
    const float* __restrict__ sldj,
    const float* __restrict__ log_p,
    const float* __restrict__ mesh_norm,
    float* __restrict__ out,
    int npts, int npairs)
{
  __shared__ __align__(16) float co[COEF_FLOATS];

  const int tid  = threadIdx.x;
  const int wv   = tid >> 6;        // 0..7
  const int lane = tid & 63;

  const int t = blockIdx.x * BLOCK + tid;
  const bool live = t < npairs;

  // ---- main-body loads first: independent of setup, can hide under it ----
  const float4* __restrict__ x4 = reinterpret_cast<const float4*>(x);
  float4 xa, xb;
  float ps = 0.f;
  if (live) {
    xa = x4[2 * t];
    xb = x4[2 * t + 1];
    ps = (t & 1) ? sldj[t >> 1] : pdj[t >> 1];
  }

  // ---- setup: 2 dims per wave, direct global reads, one barrier ----
  {
    const float mj  = mesh_norm[lane];
    const float mj1 = mesh_norm[lane + 1];
    const float mj2 = mesh_norm[(lane + 2 > ME) ? ME : (lane + 2)];
    const float es0 = mesh_norm[1];            // mesh_norm[0] == 0
    const float h = mj1 - mj;
#pragma unroll
    for (int i = 0; i < 2; ++i) {
      const int d = 2 * wv + i;
      const float ep = (lane < 63) ? __expf(log_p[lane * DIM + d]) : 0.f;
      float ss = (lane < 63) ? ep * (mj2 - mj) : 0.f;
      ss += __shfl_xor(ss, 1);  ss += __shfl_xor(ss, 2);  ss += __shfl_xor(ss, 4);
      ss += __shfl_xor(ss, 8);  ss += __shfl_xor(ss, 16); ss += __shfl_xor(ss, 32);
      const float scale = (1.0f - es0) / (0.5f * ss);
      const float cur = (lane < 63) ? ep * scale : 1.0f;   // pdf_norm[lane+1]
      float prev = __shfl_up(cur, 1);                       // pdf_norm[lane]
      if (lane == 0) prev = 1.0f;
      const float cell = (prev + cur) * 0.5f * h;
      float v = cell, o;
      o = __shfl_up(v, 1);  if (lane >= 1)  v += o;
      o = __shfl_up(v, 2);  if (lane >= 2)  v += o;
      o = __shfl_up(v, 4);  if (lane >= 4)  v += o;
      o = __shfl_up(v, 8);  if (lane >= 8)  v += o;
      o = __shfl_up(v, 16); if (lane >= 16) v += o;
      o = __shfl_up(v, 32); if (lane >= 32) v += o;
      const float F = v - cell;                             // exclusive prefix = F_ref[lane]
      const float A = 0.5f * (cur - prev) / h;
      const float B = fmaf(-(A + A), mj, prev);
      const float D = fmaf(mj, fmaf(mj, A, -prev), F);
      *reinterpret_cast<float4*>(&co[(lane + 1) * ROWF + 4 * d]) =
          make_float4(A, B, D, A + A);
    }
    // sentinel rows 0 and 65: (A,B,D,2A) = (0,1,0,0) -> y=xn, dt=1 exactly
    if (tid < 32) {
      const int row = (tid >> 4) ? (NBIN - 1) : 0;
      const int d = tid & 15;
      *reinterpret_cast<float4*>(&co[row * ROWF + 4 * d]) =
          make_float4(0.f, 1.f, 0.f, 0.f);
    }
  }
  __syncthreads();

  if (!live) return;

  // ---- one half-point (8 dims) ----
  float4* __restrict__ out4 = reinterpret_cast<float4*>(out);
  const int np16 = npts * DIM;
  const int p  = t >> 1;
  const int hh = t & 1;                       // half: dims hh*8 .. hh*8+7
  const int dbase = hh << 5;                  // float offset of dim block in a row
  const float vals[8] = {xa.x, xa.y, xa.z, xa.w, xb.x, xb.y, xb.z, xb.w};

  float xn[8];
  int   idx[8];
#pragma unroll
  for (int j = 0; j < 8; ++j) {
    const float val = vals[j];
    xn[j] = fmaf(val, 0.01f, 0.5f);
    const float u = fmaf(fabsf(val), K1, 1.0f);
    const float n = __log2f(u) * INV_L2R;
    int k = 32 + (int)ceilf(copysignf(n, val));   // searchsorted k (analytic)
    k = k < 0 ? 0 : (k > NBIN - 1 ? NBIN - 1 : k);
    idx[j] = k * ROWF + dbase + (j << 2);
  }

  float4 cf[8];
#pragma unroll
  for (int j = 0; j < 8; ++j)
    cf[j] = *reinterpret_cast<const float4*>(&co[idx[j]]);

  float yv[8], dt[8];
#pragma unroll
  for (int j = 0; j < 8; ++j) {
    const float z = xn[j];
    yv[j] = fmaf(fmaf(z, fmaf(z, cf[j].x, cf[j].y), cf[j].z), 2.0f * BOUNDF, -BOUNDF);
    dt[j] = fmaf(z, cf[j].w, cf[j].y);
  }
  const float prod = ((dt[0] * dt[1]) * (dt[2] * dt[3])) *
                     ((dt[4] * dt[5]) * (dt[6] * dt[7]));

  out4[2 * t]     = make_float4(yv[0], yv[1], yv[2], yv[3]);
  out4[2 * t + 1] = make_float4(yv[4], yv[5], yv[6], yv[7]);

  const float full = prod * __shfl_xor(prod, 1);
  const float res  = hh ? (ps + __logf(full)) : (ps * full);
  out[np16 + hh * npts + p] = res;
}

extern "C" void kernel_launch(void* const* d_in, const int* in_sizes, int n_in,
                              void* d_out, int out_size, void* d_ws, size_t ws_size,
                              hipStream_t stream) {
  const float* x    = (const float*)d_in[0];
  const float* pdj  = (const float*)d_in[1];
  const float* sldj = (const float*)d_in[2];
  const float* lp   = (const float*)d_in[3];
  const float* mesh = (const float*)d_in[4];
  float* out = (float*)d_out;

  const int npts   = in_sizes[0] / DIM;
  const int npairs = npts * 2;
  const int grid   = (npairs + BLOCK - 1) / BLOCK;    // 4096 @ 1M points

  hipLaunchKernelGGL(nll_kernel, dim3(grid), dim3(BLOCK), 0, stream,
                     x, pdj, sldj, lp, mesh, out, npts, npairs);
}